// Round 6
// baseline (159.181 us; speedup 1.0000x reference)
//
#include <hip/hip_runtime.h>
#include <math.h>

#define DMODEL 512
#define DINNER 1024
#define DTRANK 32
#define DSTATE 16
#define HW     16384   // 128*128
#define BATCH  8
#define HBATCH 4       // batches per half (128 MiB of x per half = L3/2)

typedef float vf4 __attribute__((ext_vector_type(4)));

__device__ __forceinline__ float wave_reduce(float s) {
#pragma unroll
    for (int off = 32; off; off >>= 1) s += __shfl_xor(s, off);
    return s;
}

__device__ __forceinline__ float dot4(vf4 a, vf4 b) {
    return a.x * b.x + a.y * b.y + a.z * b.z + a.w * b.w;
}

// ---------------------------------------------------------------------------
// Kernel 1: mean over spatial dims for one half (4 batches = 2048 rows).
// Leaves this half of x resident in Infinity Cache for the mul pass.
// ---------------------------------------------------------------------------
__global__ __launch_bounds__(256) void mean_kernel(const float* __restrict__ x,
                                                   float* __restrict__ mean_out,
                                                   int b0) {
    const int row = b0 * DMODEL + blockIdx.x;          // 2048 rows per half
    const vf4* xr = (const vf4*)(x + (size_t)row * HW);
    const int t = threadIdx.x;
    float s = 0.f;
#pragma unroll
    for (int j = 0; j < 16; ++j) {
        vf4 v = xr[t + j * 256];
        s += v.x + v.y + v.z + v.w;
    }
    for (int off = 32; off; off >>= 1) s += __shfl_down(s, off);
    __shared__ float part[4];
    if ((t & 63) == 0) part[t >> 6] = s;
    __syncthreads();
    if (t == 0) {
        float tot = part[0] + part[1] + part[2] + part[3];
        mean_out[row] = tot * (1.0f / (float)HW);
    }
}

// ---------------------------------------------------------------------------
// K2a: xz = W_in @ u for 4 batches, fused conv(tap-3)+silu. One block per
// W_in row e (2048 blocks); wave wv handles batch b0+wv.
// ---------------------------------------------------------------------------
__global__ __launch_bounds__(256) void k2a_win_kernel(
    const float* __restrict__ mean_in,   // (8,512)
    const float* __restrict__ W_in,      // (2048,512)
    const float* __restrict__ conv_w,    // (1024,4)
    const float* __restrict__ conv_b,    // (1024,)
    float* __restrict__ xs_buf,          // (8,1024)
    float* __restrict__ sz_buf,          // (8,1024)
    int b0)
{
    const int e = blockIdx.x;                          // 0..2047
    const int t = threadIdx.x;
    const int lane = t & 63;
    const int b = b0 + (t >> 6);                       // batch for this wave

    const vf4* row = (const vf4*)(W_in + (size_t)e * DMODEL);
    const vf4 w0 = row[lane];
    const vf4 w1 = row[lane + 64];
    const vf4* u4 = (const vf4*)mean_in;

    vf4 a = u4[b * 128 + lane];
    vf4 c = u4[b * 128 + lane + 64];
    float acc = dot4(w0, a) + dot4(w1, c);
    acc = wave_reduce(acc);

    if (lane == 0) {
        if (e < DINNER) {
            float xc = acc * conv_w[e * 4 + 3] + conv_b[e];
            xs_buf[b * DINNER + e] = xc / (1.f + expf(-xc));
        } else {
            const int d = e - DINNER;
            sz_buf[b * DINNER + d] = acc / (1.f + expf(-acc));
        }
    }
}

// ---------------------------------------------------------------------------
// K2b: per batch: x_dbl = W_x @ xs; bc = dot(B,C); delta = softplus(W_dt@dt+b);
//      y = (delta*bc + D)*xs*silu(z).  HBATCH blocks x 512 threads.
// ---------------------------------------------------------------------------
__global__ __launch_bounds__(512) void k2b_mid_kernel(
    const float* __restrict__ xs_buf,    // (8,1024)
    const float* __restrict__ sz_buf,    // (8,1024)
    const float* __restrict__ W_x,       // (64,1024)
    const float* __restrict__ W_dt,      // (1024,32)
    const float* __restrict__ b_dt,      // (1024,)
    const float* __restrict__ D_param,   // (1024,)
    float* __restrict__ yv_buf,          // (8,1024)
    int b0)
{
    __shared__ float xs[DINNER];
    __shared__ float xdbl[64];
    const int b = b0 + blockIdx.x;
    const int t = threadIdx.x;
    const int lane = t & 63;
    const int wv = t >> 6;                             // 0..7

#pragma unroll
    for (int i = 0; i < 2; ++i) xs[t + i * 512] = xs_buf[b * DINNER + t + i * 512];
    __syncthreads();

    const vf4* xs4 = (const vf4*)xs;
    for (int oi = 0; oi < 8; ++oi) {
        const int o = wv * 8 + oi;
        const vf4* wr = (const vf4*)(W_x + (size_t)o * DINNER);
        float acc = 0.f;
#pragma unroll
        for (int j = 0; j < 4; ++j)
            acc += dot4(wr[lane + j * 64], xs4[lane + j * 64]);
        acc = wave_reduce(acc);
        if (lane == 0) xdbl[o] = acc;
    }
    __syncthreads();

    float bc = 0.f;
#pragma unroll
    for (int n = 0; n < DSTATE; ++n)
        bc += xdbl[DTRANK + n] * xdbl[DTRANK + DSTATE + n];

#pragma unroll
    for (int k = 0; k < 2; ++k) {
        const int d = t + k * 512;
        float acc = b_dt[d];
        const vf4* wr = (const vf4*)(W_dt + (size_t)d * DTRANK);
        const vf4* dt4 = (const vf4*)xdbl;
#pragma unroll
        for (int r = 0; r < 8; ++r)
            acc += dot4(wr[r], dt4[r]);
        float delta = (acc > 20.f) ? acc : log1pf(expf(acc));
        yv_buf[b * DINNER + d] =
            (delta * bc + D_param[d]) * xs[d] * sz_buf[b * DINNER + d];
    }
}

// ---------------------------------------------------------------------------
// Kernel 3: per (b,c) row: gate = sigmoid(W_out[c,:].yv[b,:]) per-wave, then
// low-VGPR load-mul-store stream. x rows for this half are L3-resident from
// the mean pass; nt stores keep out from competing where honored.
// ---------------------------------------------------------------------------
__global__ __launch_bounds__(256) void gate_mul_kernel(
    const float* __restrict__ x,
    const float* __restrict__ yv_buf,    // (8,1024)
    const float* __restrict__ W_out,     // (512,1024)
    float* __restrict__ out,
    int b0)
{
    const int row = b0 * DMODEL + blockIdx.x;          // 2048 rows per half
    const int b = row >> 9;
    const int c = row & 511;
    const int t = threadIdx.x;
    const int lane = t & 63;

    const vf4* wr = (const vf4*)(W_out + (size_t)c * DINNER);
    const vf4* yv = (const vf4*)(yv_buf + (size_t)b * DINNER);
    float acc = 0.f;
#pragma unroll
    for (int j = 0; j < 4; ++j)
        acc += dot4(wr[lane + j * 64], yv[lane + j * 64]);
    acc = wave_reduce(acc);
    const float g = 1.f / (1.f + expf(-acc));

    const vf4* xi = (const vf4*)(x + (size_t)row * HW);
    vf4* oo = (vf4*)(out + (size_t)row * HW);
#pragma unroll 4
    for (int j = 0; j < 16; ++j) {
        vf4 v = xi[t + j * 256] * g;
        __builtin_nontemporal_store(v, &oo[t + j * 256]);
    }
}

extern "C" void kernel_launch(void* const* d_in, const int* in_sizes, int n_in,
                              void* d_out, int out_size, void* d_ws, size_t ws_size,
                              hipStream_t stream) {
    const float* x       = (const float*)d_in[0];
    const float* W_in    = (const float*)d_in[1];
    const float* conv_w  = (const float*)d_in[2];
    const float* conv_b  = (const float*)d_in[3];
    const float* W_x     = (const float*)d_in[4];
    const float* W_dt    = (const float*)d_in[5];
    const float* b_dt    = (const float*)d_in[6];
    // d_in[7] = A_log — mathematically dead at L=1 (h0 = 0)
    const float* D_param = (const float*)d_in[8];
    const float* W_out   = (const float*)d_in[9];
    float* out = (float*)d_out;

    float* mean_buf = (float*)d_ws;                  // 4096
    float* xs_buf   = mean_buf + BATCH * DMODEL;     // 8192
    float* sz_buf   = xs_buf + BATCH * DINNER;       // 8192
    float* yv_buf   = sz_buf + BATCH * DINNER;       // 8192

    for (int half = 0; half < 2; ++half) {
        const int b0 = half * HBATCH;
        mean_kernel<<<HBATCH * DMODEL, 256, 0, stream>>>(x, mean_buf, b0);
        k2a_win_kernel<<<2048, 256, 0, stream>>>(mean_buf, W_in, conv_w, conv_b,
                                                 xs_buf, sz_buf, b0);
        k2b_mid_kernel<<<HBATCH, 512, 0, stream>>>(xs_buf, sz_buf, W_x, W_dt,
                                                   b_dt, D_param, yv_buf, b0);
        gate_mul_kernel<<<HBATCH * DMODEL, 256, 0, stream>>>(x, yv_buf, W_out,
                                                             out, b0);
    }
}

// Round 7
// 144.269 us; speedup vs baseline: 1.1034x; 1.1034x over previous
//
#include <hip/hip_runtime.h>
#include <math.h>

#define DMODEL 512
#define DINNER 1024
#define DTRANK 32
#define DSTATE 16
#define HW     16384   // 128*128
#define BATCH  8

typedef float vf4 __attribute__((ext_vector_type(4)));

__device__ __forceinline__ float wave_reduce(float s) {
#pragma unroll
    for (int off = 32; off; off >>= 1) s += __shfl_xor(s, off);
    return s;
}

__device__ __forceinline__ float dot4(vf4 a, vf4 b) {
    return a.x * b.x + a.y * b.y + a.z * b.z + a.w * b.w;
}

// ---------------------------------------------------------------------------
// Kernel 1: mean over spatial dims. One block per (b,c) row of 16384 floats.
// ---------------------------------------------------------------------------
__global__ __launch_bounds__(256) void mean_kernel(const float* __restrict__ x,
                                                   float* __restrict__ mean_out) {
    const int row = blockIdx.x;                       // b*512 + c  (4096 rows)
    const vf4* xr = (const vf4*)(x + (size_t)row * HW);
    const int t = threadIdx.x;
    float s = 0.f;
#pragma unroll
    for (int j = 0; j < 16; ++j) {                    // 4096 float4 / 256 thr
        vf4 v = xr[t + j * 256];
        s += v.x + v.y + v.z + v.w;
    }
    for (int off = 32; off; off >>= 1) s += __shfl_down(s, off);
    __shared__ float part[4];
    if ((t & 63) == 0) part[t >> 6] = s;
    __syncthreads();
    if (t == 0) {
        float tot = part[0] + part[1] + part[2] + part[3];
        mean_out[row] = tot * (1.0f / (float)HW);
    }
}

// ---------------------------------------------------------------------------
// K2a: xz = W_in @ u, fused conv(tap-3)+silu epilogue. One block per W_in row
// (2048 blocks); the 4 waves each own 2 batches; W_in row shared via L1.
// ---------------------------------------------------------------------------
__global__ __launch_bounds__(256) void k2a_win_kernel(
    const float* __restrict__ mean_in,   // (8,512)
    const float* __restrict__ W_in,      // (2048,512)
    const float* __restrict__ conv_w,    // (1024,4)
    const float* __restrict__ conv_b,    // (1024,)
    float* __restrict__ xs_buf,          // (8,1024)
    float* __restrict__ sz_buf)          // (8,1024)
{
    const int e = blockIdx.x;                         // 0..2047
    const int t = threadIdx.x;
    const int lane = t & 63;
    const int wv = t >> 6;                            // 0..3 -> batches 2wv,2wv+1

    const vf4* row = (const vf4*)(W_in + (size_t)e * DMODEL);
    const vf4 w0 = row[lane];
    const vf4 w1 = row[lane + 64];
    const vf4* u4 = (const vf4*)mean_in;

    float acc[2];
#pragma unroll
    for (int k = 0; k < 2; ++k) {
        const int b = wv * 2 + k;
        vf4 a = u4[b * 128 + lane];
        vf4 c = u4[b * 128 + lane + 64];
        acc[k] = dot4(w0, a) + dot4(w1, c);
        acc[k] = wave_reduce(acc[k]);
    }

    if (lane == 0) {
        if (e < DINNER) {
            const float cw = conv_w[e * 4 + 3];
            const float cb = conv_b[e];
#pragma unroll
            for (int k = 0; k < 2; ++k) {
                float xc = acc[k] * cw + cb;
                xs_buf[(wv * 2 + k) * DINNER + e] = xc / (1.f + expf(-xc));
            }
        } else {
            const int d = e - DINNER;
#pragma unroll
            for (int k = 0; k < 2; ++k) {
                float zc = acc[k];
                sz_buf[(wv * 2 + k) * DINNER + d] = zc / (1.f + expf(-zc));
            }
        }
    }
}

// ---------------------------------------------------------------------------
// K2b: per batch: x_dbl = W_x @ xs; bc = dot(B,C); delta = softplus(W_dt@dt+b);
//      y = (delta*bc + D)*xs*silu(z).  8 blocks x 512 threads.
// ---------------------------------------------------------------------------
__global__ __launch_bounds__(512) void k2b_mid_kernel(
    const float* __restrict__ xs_buf,    // (8,1024)
    const float* __restrict__ sz_buf,    // (8,1024)
    const float* __restrict__ W_x,       // (64,1024)
    const float* __restrict__ W_dt,      // (1024,32)
    const float* __restrict__ b_dt,      // (1024,)
    const float* __restrict__ D_param,   // (1024,)
    float* __restrict__ yv_buf)          // (8,1024)
{
    __shared__ float xs[DINNER];
    __shared__ float xdbl[64];
    const int b = blockIdx.x;
    const int t = threadIdx.x;
    const int lane = t & 63;
    const int wv = t >> 6;                            // 0..7

#pragma unroll
    for (int i = 0; i < 2; ++i) xs[t + i * 512] = xs_buf[b * DINNER + t + i * 512];
    __syncthreads();

    // x_dbl: 64 outputs, 8 waves x 8 outputs each; lanes split the 1024-dot
    const vf4* xs4 = (const vf4*)xs;
    for (int oi = 0; oi < 8; ++oi) {
        const int o = wv * 8 + oi;
        const vf4* wr = (const vf4*)(W_x + (size_t)o * DINNER);
        float acc = 0.f;
#pragma unroll
        for (int j = 0; j < 4; ++j)
            acc += dot4(wr[lane + j * 64], xs4[lane + j * 64]);
        acc = wave_reduce(acc);
        if (lane == 0) xdbl[o] = acc;
    }
    __syncthreads();

    float bc = 0.f;
#pragma unroll
    for (int n = 0; n < DSTATE; ++n)
        bc += xdbl[DTRANK + n] * xdbl[DTRANK + DSTATE + n];

#pragma unroll
    for (int k = 0; k < 2; ++k) {
        const int d = t + k * 512;
        float acc = b_dt[d];
        const vf4* wr = (const vf4*)(W_dt + (size_t)d * DTRANK);
        const vf4* dt4 = (const vf4*)xdbl;
#pragma unroll
        for (int r = 0; r < 8; ++r)
            acc += dot4(wr[r], dt4[r]);
        float delta = (acc > 20.f) ? acc : log1pf(expf(acc));
        yv_buf[b * DINNER + d] =
            (delta * bc + D_param[d]) * xs[d] * sz_buf[b * DINNER + d];
    }
}

// ---------------------------------------------------------------------------
// Kernel 3: per (b,c) row: gate = sigmoid(W_out[c,:] . yv[b,:]) computed
// redundantly per wave, then a low-VGPR load-mul-store stream of the row with
// NONTEMPORAL stores. Reverse traversal ping-pongs L3 residency with the mean
// pass's forward read.
// ---------------------------------------------------------------------------
__global__ __launch_bounds__(256, 6) void gate_mul_kernel(
    const float* __restrict__ x,
    const float* __restrict__ yv_buf,    // (8,1024)
    const float* __restrict__ W_out,     // (512,1024)
    float* __restrict__ out)
{
    const int row = (BATCH * DMODEL - 1) - blockIdx.x;   // reverse traversal
    const int b = row >> 9;
    const int c = row & 511;
    const int t = threadIdx.x;
    const int lane = t & 63;

    const vf4* wr = (const vf4*)(W_out + (size_t)c * DINNER);
    const vf4* yv = (const vf4*)(yv_buf + (size_t)b * DINNER);
    float acc = 0.f;
#pragma unroll
    for (int j = 0; j < 4; ++j)
        acc += dot4(wr[lane + j * 64], yv[lane + j * 64]);
    acc = wave_reduce(acc);
    const float g = 1.f / (1.f + expf(-acc));

    const vf4* xi = (const vf4*)(x + (size_t)row * HW);
    vf4* oo = (vf4*)(out + (size_t)row * HW);
#pragma unroll 4
    for (int j = 0; j < 16; ++j) {
        vf4 v = xi[t + j * 256] * g;
        __builtin_nontemporal_store(v, &oo[t + j * 256]);
    }
}

extern "C" void kernel_launch(void* const* d_in, const int* in_sizes, int n_in,
                              void* d_out, int out_size, void* d_ws, size_t ws_size,
                              hipStream_t stream) {
    const float* x       = (const float*)d_in[0];
    const float* W_in    = (const float*)d_in[1];
    const float* conv_w  = (const float*)d_in[2];
    const float* conv_b  = (const float*)d_in[3];
    const float* W_x     = (const float*)d_in[4];
    const float* W_dt    = (const float*)d_in[5];
    const float* b_dt    = (const float*)d_in[6];
    // d_in[7] = A_log — mathematically dead at L=1 (h0 = 0)
    const float* D_param = (const float*)d_in[8];
    const float* W_out   = (const float*)d_in[9];
    float* out = (float*)d_out;

    float* mean_buf = (float*)d_ws;                  // 4096
    float* xs_buf   = mean_buf + BATCH * DMODEL;     // 8192
    float* sz_buf   = xs_buf + BATCH * DINNER;       // 8192
    float* yv_buf   = sz_buf + BATCH * DINNER;       // 8192

    mean_kernel<<<BATCH * DMODEL, 256, 0, stream>>>(x, mean_buf);
    k2a_win_kernel<<<2048, 256, 0, stream>>>(mean_buf, W_in, conv_w, conv_b,
                                             xs_buf, sz_buf);
    k2b_mid_kernel<<<BATCH, 512, 0, stream>>>(xs_buf, sz_buf, W_x, W_dt, b_dt,
                                              D_param, yv_buf);
    gate_mul_kernel<<<BATCH * DMODEL, 256, 0, stream>>>(x, yv_buf, W_out, out);
}